// Round 1
// baseline (846.855 us; speedup 1.0000x reference)
//
#include <hip/hip_runtime.h>
#include <math.h>

#define N_NODES 100000
#define N_EDGES 1600000

static inline size_t align256(size_t x) { return (x + 255) & ~((size_t)255); }

constexpr int SCAN_T = 1024;
constexpr int NCHUNK = (N_NODES + SCAN_T - 1) / SCAN_T;  // 98

// ---------------- CSR build ----------------

__global__ void hist_kernel(const int* __restrict__ dst, int* __restrict__ cnt) {
  int e = blockIdx.x * blockDim.x + threadIdx.x;
  if (e < N_EDGES) atomicAdd(&cnt[dst[e]], 1);
}

__global__ __launch_bounds__(1024) void scan1_kernel(const int* __restrict__ cnt,
                                                     int* __restrict__ rowptr,
                                                     int* __restrict__ blocksum) {
  __shared__ int s[SCAN_T];
  int t = threadIdx.x;
  int i = blockIdx.x * SCAN_T + t;
  int v = (i < N_NODES) ? cnt[i] : 0;
  s[t] = v;
  __syncthreads();
  for (int off = 1; off < SCAN_T; off <<= 1) {
    int add = (t >= off) ? s[t - off] : 0;
    __syncthreads();
    s[t] += add;
    __syncthreads();
  }
  if (i < N_NODES) rowptr[i] = s[t] - v;  // exclusive
  if (t == SCAN_T - 1) blocksum[blockIdx.x] = s[t];
}

__global__ void scan2_kernel(int* __restrict__ blocksum, int nb) {
  __shared__ int s[128];
  int t = threadIdx.x;  // 128 threads
  int v = (t < nb) ? blocksum[t] : 0;
  s[t] = v;
  __syncthreads();
  for (int off = 1; off < 128; off <<= 1) {
    int add = (t >= off) ? s[t - off] : 0;
    __syncthreads();
    s[t] += add;
    __syncthreads();
  }
  if (t < nb) blocksum[t] = s[t] - v;  // exclusive block offsets
}

__global__ __launch_bounds__(1024) void scan3_kernel(int* __restrict__ rowptr,
                                                     int* __restrict__ fill,
                                                     const int* __restrict__ blocksum) {
  int i = blockIdx.x * SCAN_T + threadIdx.x;
  if (i < N_NODES) {
    int r = rowptr[i] + blocksum[blockIdx.x];
    rowptr[i] = r;
    fill[i] = r;
  }
}

// scatter col[] and accumulate coef[src] += 1/cnt[dst] in one edge pass
__global__ void scatter_coef_kernel(const int* __restrict__ src, const int* __restrict__ dst,
                                    const int* __restrict__ cnt, int* __restrict__ fill,
                                    int* __restrict__ col, float* __restrict__ coef) {
  int e = blockIdx.x * blockDim.x + threadIdx.x;
  if (e < N_EDGES) {
    int d = dst[e];
    int sN = src[e];
    int p = atomicAdd(&fill[d], 1);
    col[p] = sN;
    atomicAdd(&coef[sN], 1.0f / (float)cnt[d]);
  }
}

// ---------------- fused SAGEConv + BN + ReLU (layers 0 and 1) ----------------
// one wave per node; lane = feature channel

__global__ __launch_bounds__(256) void layer_kernel(
    const float* __restrict__ hin, const int* __restrict__ rowptr,
    const int* __restrict__ cnt, const int* __restrict__ col,
    const float* __restrict__ wl, const float* __restrict__ bl,
    const float* __restrict__ wr,
    const float* __restrict__ g, const float* __restrict__ be,
    const float* __restrict__ m, const float* __restrict__ v,
    float* __restrict__ hout) {
  __shared__ float wlT[4096];  // wlT[k*64+j] = wl[j][k]
  __shared__ float wrT[4096];
  __shared__ float scaleS[64], shiftS[64], biasS[64];
  __shared__ float aggrS[4][64];
  __shared__ float ownS[4][64];

  int tid = threadIdx.x;
  for (int i = tid; i < 4096; i += 256) {
    int j = i >> 6, k = i & 63;
    wlT[k * 64 + j] = wl[i];
    wrT[k * 64 + j] = wr[i];
  }
  if (tid < 64) {
    float rs = rsqrtf(v[tid] + 1e-5f);
    float sc = rs * g[tid];
    scaleS[tid] = sc;
    shiftS[tid] = be[tid] - m[tid] * sc;
    biasS[tid] = bl[tid];
  }
  __syncthreads();

  const int lane = tid & 63;
  const int wv = tid >> 6;
  const int stride = gridDim.x * 4;
  for (int node = blockIdx.x * 4 + wv; node < N_NODES; node += stride) {
    float own = hin[(size_t)node * 64 + lane];
    int start = rowptr[node];
    int deg = cnt[node];
    float a0 = 0.f, a1 = 0.f;
    int e2 = 0;
    for (; e2 + 2 <= deg; e2 += 2) {
      int s0 = col[start + e2];
      int s1 = col[start + e2 + 1];
      a0 += hin[(size_t)s0 * 64 + lane];
      a1 += hin[(size_t)s1 * 64 + lane];
    }
    if (e2 < deg) a0 += hin[(size_t)col[start + e2] * 64 + lane];
    float acc = a0 + a1;
    float aggr = (deg > 0) ? (acc / (float)deg) : 0.f;

    aggrS[wv][lane] = aggr;  // wave-internal LDS exchange, no barrier needed
    ownS[wv][lane] = own;

    float o0 = 0.f, o1 = 0.f, o2 = 0.f, o3 = 0.f;
#pragma unroll
    for (int k = 0; k < 64; k += 2) {
      o0 += wlT[k * 64 + lane] * aggrS[wv][k];
      o1 += wrT[k * 64 + lane] * ownS[wv][k];
      o2 += wlT[(k + 1) * 64 + lane] * aggrS[wv][k + 1];
      o3 += wrT[(k + 1) * 64 + lane] * ownS[wv][k + 1];
    }
    float out = biasS[lane] + ((o0 + o2) + (o1 + o3));
    out = fmaxf(out * scaleS[lane] + shiftS[lane], 0.f);
    hout[(size_t)node * 64 + lane] = out;
  }
}

// ---------------- reduction over h2: sums[0:64]=Σ h2, sums[64:128]=Σ coef*h2 ----------------

__global__ __launch_bounds__(256) void reduce_kernel(const float* __restrict__ h2,
                                                     const float* __restrict__ coef,
                                                     float* __restrict__ sums) {
  int lane = threadIdx.x & 63;
  int wv = threadIdx.x >> 6;
  int gwave = blockIdx.x * 4 + wv;
  int stride = gridDim.x * 4;
  float s0 = 0.f, s1 = 0.f;
  for (int node = gwave; node < N_NODES; node += stride) {
    float val = h2[(size_t)node * 64 + lane];
    float c = coef[node];
    s0 += val;
    s1 += c * val;
  }
  atomicAdd(&sums[lane], s0);
  atomicAdd(&sums[64 + lane], s1);
}

// ---------------- collapsed layer 2 + classifier + sigmoid ----------------

__global__ void final_kernel(const float* __restrict__ sums,
                             const float* __restrict__ wl2, const float* __restrict__ bl2,
                             const float* __restrict__ wr2,
                             const float* __restrict__ cw1, const float* __restrict__ cb1,
                             const float* __restrict__ cw2, const float* __restrict__ cb2,
                             float* __restrict__ out) {
  __shared__ float maS[64], mhS[64], m3S[64], tS[64];
  int j = threadIdx.x;  // 64 threads
  float invN = 1.0f / (float)N_NODES;
  mhS[j] = sums[j] * invN;        // mean of h2
  maS[j] = sums[64 + j] * invN;   // mean of aggr3
  __syncthreads();
  float acc = bl2[j];
#pragma unroll
  for (int k = 0; k < 64; ++k)
    acc += wl2[j * 64 + k] * maS[k] + wr2[j * 64 + k] * mhS[k];
  m3S[j] = acc;
  __syncthreads();
  float c = cb1[j];
#pragma unroll
  for (int k = 0; k < 64; ++k) c += cw1[j * 64 + k] * m3S[k];
  tS[j] = fmaxf(c, 0.f);
  __syncthreads();
  float r = tS[j] * cw2[j];
#pragma unroll
  for (int off = 32; off > 0; off >>= 1) r += __shfl_down(r, off);
  if (j == 0) out[0] = 1.0f / (1.0f + expf(-(r + cb2[0])));
}

// ---------------- host launcher ----------------

extern "C" void kernel_launch(void* const* d_in, const int* in_sizes, int n_in,
                              void* d_out, int out_size, void* d_ws, size_t ws_size,
                              hipStream_t stream) {
  const float* x   = (const float*)d_in[0];
  const int* ei    = (const int*)d_in[1];
  const float* wl0 = (const float*)d_in[2];
  const float* bl0 = (const float*)d_in[3];
  const float* wr0 = (const float*)d_in[4];
  const float* wl1 = (const float*)d_in[5];
  const float* bl1 = (const float*)d_in[6];
  const float* wr1 = (const float*)d_in[7];
  const float* wl2 = (const float*)d_in[8];
  const float* bl2 = (const float*)d_in[9];
  const float* wr2 = (const float*)d_in[10];
  const float* g0  = (const float*)d_in[11];
  const float* be0 = (const float*)d_in[12];
  const float* m0  = (const float*)d_in[13];
  const float* v0  = (const float*)d_in[14];
  const float* g1  = (const float*)d_in[15];
  const float* be1 = (const float*)d_in[16];
  const float* m1  = (const float*)d_in[17];
  const float* v1  = (const float*)d_in[18];
  const float* cw1 = (const float*)d_in[19];
  const float* cb1 = (const float*)d_in[20];
  const float* cw2 = (const float*)d_in[21];
  const float* cb2 = (const float*)d_in[22];

  const int* srcp = ei;            // edge_index[0]
  const int* dstp = ei + N_EDGES;  // edge_index[1]

  char* ws = (char*)d_ws;
  size_t off = 0;
  auto alloc = [&](size_t bytes) {
    void* p = ws + off;
    off = align256(off + bytes);
    return p;
  };
  int* cnt      = (int*)alloc((size_t)N_NODES * 4);
  int* rowptr   = (int*)alloc((size_t)N_NODES * 4);
  int* fill     = (int*)alloc((size_t)N_NODES * 4);
  int* blocksum = (int*)alloc(128 * 4);
  float* coef   = (float*)alloc((size_t)N_NODES * 4);
  int* col      = (int*)alloc((size_t)N_EDGES * 4);
  float* sums   = (float*)alloc(128 * 4);
  float* h1     = (float*)alloc((size_t)N_NODES * 64 * 4);
  float* h2     = (float*)alloc((size_t)N_NODES * 64 * 4);
  (void)off; (void)ws_size; (void)in_sizes; (void)n_in; (void)out_size;

  hipMemsetAsync(cnt, 0, (size_t)N_NODES * 4, stream);
  hipMemsetAsync(coef, 0, (size_t)N_NODES * 4, stream);
  hipMemsetAsync(sums, 0, 128 * 4, stream);

  int eg = (N_EDGES + 255) / 256;
  hist_kernel<<<eg, 256, 0, stream>>>(dstp, cnt);
  scan1_kernel<<<NCHUNK, SCAN_T, 0, stream>>>(cnt, rowptr, blocksum);
  scan2_kernel<<<1, 128, 0, stream>>>(blocksum, NCHUNK);
  scan3_kernel<<<NCHUNK, SCAN_T, 0, stream>>>(rowptr, fill, blocksum);
  scatter_coef_kernel<<<eg, 256, 0, stream>>>(srcp, dstp, cnt, fill, col, coef);

  layer_kernel<<<1024, 256, 0, stream>>>(x, rowptr, cnt, col, wl0, bl0, wr0,
                                         g0, be0, m0, v0, h1);
  layer_kernel<<<1024, 256, 0, stream>>>(h1, rowptr, cnt, col, wl1, bl1, wr1,
                                         g1, be1, m1, v1, h2);
  reduce_kernel<<<256, 256, 0, stream>>>(h2, coef, sums);
  final_kernel<<<1, 64, 0, stream>>>(sums, wl2, bl2, wr2, cw1, cb1, cw2, cb2,
                                     (float*)d_out);
}

// Round 2
// 456.385 us; speedup vs baseline: 1.8556x; 1.8556x over previous
//
#include <hip/hip_runtime.h>
#include <math.h>

#define N_NODES 100000
#define N_EDGES 1600000

static inline size_t align256(size_t x) { return (x + 255) & ~((size_t)255); }

constexpr int SCAN_T = 1024;
constexpr int NCHUNK = (N_NODES + SCAN_T - 1) / SCAN_T;  // 98

// ---------------- CSR build ----------------

__global__ void hist_kernel(const int* __restrict__ dst, int* __restrict__ cnt) {
  int i = blockIdx.x * blockDim.x + threadIdx.x;
  if (i < N_EDGES / 4) {
    int4 d = ((const int4*)dst)[i];
    atomicAdd(&cnt[d.x], 1);
    atomicAdd(&cnt[d.y], 1);
    atomicAdd(&cnt[d.z], 1);
    atomicAdd(&cnt[d.w], 1);
  }
}

__global__ __launch_bounds__(1024) void scan1_kernel(const int* __restrict__ cnt,
                                                     int* __restrict__ rowptr,
                                                     int* __restrict__ blocksum) {
  __shared__ int s[SCAN_T];
  int t = threadIdx.x;
  int i = blockIdx.x * SCAN_T + t;
  int v = (i < N_NODES) ? cnt[i] : 0;
  s[t] = v;
  __syncthreads();
  for (int off = 1; off < SCAN_T; off <<= 1) {
    int add = (t >= off) ? s[t - off] : 0;
    __syncthreads();
    s[t] += add;
    __syncthreads();
  }
  if (i < N_NODES) rowptr[i] = s[t] - v;  // exclusive
  if (t == SCAN_T - 1) blocksum[blockIdx.x] = s[t];
}

__global__ void scan2_kernel(int* __restrict__ blocksum, int nb) {
  __shared__ int s[128];
  int t = threadIdx.x;  // 128 threads
  int v = (t < nb) ? blocksum[t] : 0;
  s[t] = v;
  __syncthreads();
  for (int off = 1; off < 128; off <<= 1) {
    int add = (t >= off) ? s[t - off] : 0;
    __syncthreads();
    s[t] += add;
    __syncthreads();
  }
  if (t < nb) blocksum[t] = s[t] - v;  // exclusive block offsets
}

__global__ __launch_bounds__(1024) void scan3_kernel(int* __restrict__ rowptr,
                                                     int* __restrict__ fill,
                                                     const int* __restrict__ blocksum) {
  int i = blockIdx.x * SCAN_T + threadIdx.x;
  if (i < N_NODES) {
    int r = rowptr[i] + blocksum[blockIdx.x];
    rowptr[i] = r;
    fill[i] = r;
  }
}

// scatter col[] and accumulate coef[src] += 1/cnt[dst] in one edge pass
__global__ void scatter_coef_kernel(const int* __restrict__ src, const int* __restrict__ dst,
                                    const int* __restrict__ cnt, int* __restrict__ fill,
                                    int* __restrict__ col, float* __restrict__ coef) {
  int i = blockIdx.x * blockDim.x + threadIdx.x;
  if (i < N_EDGES / 4) {
    int4 s4 = ((const int4*)src)[i];
    int4 d4 = ((const int4*)dst)[i];
#define EDGE_ONE(S, D)                                  \
    {                                                   \
      int p = atomicAdd(&fill[(D)], 1);                 \
      col[p] = (S);                                     \
      atomicAdd(&coef[(S)], 1.0f / (float)cnt[(D)]);    \
    }
    EDGE_ONE(s4.x, d4.x)
    EDGE_ONE(s4.y, d4.y)
    EDGE_ONE(s4.z, d4.z)
    EDGE_ONE(s4.w, d4.w)
#undef EDGE_ONE
  }
}

// ---------------- fused SAGEConv + BN + ReLU (layers 0 and 1) ----------------
// block = 512 threads = 8 waves. Each wave processes 8 nodes per round:
//  phase 1: gather (4 node-slots x 16 lanes x float4), 2 sub-rounds -> LDS exchange
//  phase 2: lane = output channel j; weights read once per 8 nodes (b128),
//           exchange reads are wave-wide broadcasts (conflict-free).

__global__ __launch_bounds__(512) void layer_kernel(
    const float* __restrict__ hin, const int* __restrict__ rowptr,
    const int* __restrict__ cnt, const int* __restrict__ col,
    const float* __restrict__ wl, const float* __restrict__ bl,
    const float* __restrict__ wr,
    const float* __restrict__ g, const float* __restrict__ be,
    const float* __restrict__ m, const float* __restrict__ v,
    float* __restrict__ hout) {
  // wwS[k2*64+j] = {wl[j][2k2], wr[j][2k2], wl[j][2k2+1], wr[j][2k2+1]}
  __shared__ float4 wwS[2048];            // 32 KB
  // exS[wave][node][k2] = {aggr[2k2], own[2k2], aggr[2k2+1], own[2k2+1]}, pad 33 for banks
  __shared__ float4 exS[8][8][33];        // 33 KB
  __shared__ float scaleS[64], shiftS[64], biasS[64];

  const int tid = threadIdx.x;
  for (int idx = tid; idx < 2048; idx += 512) {
    int k2 = idx >> 6, j = idx & 63;
    wwS[idx] = make_float4(wl[j * 64 + 2 * k2], wr[j * 64 + 2 * k2],
                           wl[j * 64 + 2 * k2 + 1], wr[j * 64 + 2 * k2 + 1]);
  }
  if (tid < 64) {
    float sc = rsqrtf(v[tid] + 1e-5f) * g[tid];
    scaleS[tid] = sc;
    shiftS[tid] = be[tid] - m[tid] * sc;
    biasS[tid] = bl[tid];
  }
  __syncthreads();

  const int lane = tid & 63;
  const int wv = tid >> 6;
  const int slot = lane >> 4;   // 0..3 node slot
  const int c = lane & 15;      // channel quad
  const int c4 = c * 4;
  const int wid = blockIdx.x * 8 + wv;
  const int nwaves = gridDim.x * 8;

  for (int gidx = wid; gidx < (N_NODES / 8); gidx += nwaves) {
    const int nbase = gidx * 8;

    // ---- phase 1: gather 8 nodes ----
#pragma unroll
    for (int sub = 0; sub < 2; ++sub) {
      const int node = nbase + sub * 4 + slot;
      const float4 own = *(const float4*)(hin + (size_t)node * 64 + c4);
      const int start = rowptr[node];
      const int deg = cnt[node];
      const int* cp = col + start;
      float ax = 0.f, ay = 0.f, az = 0.f, aw = 0.f;
      int e = 0;
      for (; e + 4 <= deg; e += 4) {
        int s0 = cp[e], s1 = cp[e + 1], s2 = cp[e + 2], s3 = cp[e + 3];
        float4 v0 = *(const float4*)(hin + (size_t)s0 * 64 + c4);
        float4 v1 = *(const float4*)(hin + (size_t)s1 * 64 + c4);
        float4 v2 = *(const float4*)(hin + (size_t)s2 * 64 + c4);
        float4 v3 = *(const float4*)(hin + (size_t)s3 * 64 + c4);
        ax += (v0.x + v1.x) + (v2.x + v3.x);
        ay += (v0.y + v1.y) + (v2.y + v3.y);
        az += (v0.z + v1.z) + (v2.z + v3.z);
        aw += (v0.w + v1.w) + (v2.w + v3.w);
      }
      for (; e < deg; ++e) {
        float4 v0 = *(const float4*)(hin + (size_t)cp[e] * 64 + c4);
        ax += v0.x; ay += v0.y; az += v0.z; aw += v0.w;
      }
      const float inv = (deg > 0) ? (1.0f / (float)deg) : 0.0f;
      ax *= inv; ay *= inv; az *= inv; aw *= inv;
      const int n = sub * 4 + slot;
      exS[wv][n][2 * c]     = make_float4(ax, own.x, ay, own.y);
      exS[wv][n][2 * c + 1] = make_float4(az, own.z, aw, own.w);
    }
    // same-wave produce/consume; compiler inserts lgkmcnt waits — no barrier needed

    // ---- phase 2: transform, lane = output channel j ----
    float out[8] = {0.f, 0.f, 0.f, 0.f, 0.f, 0.f, 0.f, 0.f};
#pragma unroll 4
    for (int k2 = 0; k2 < 32; ++k2) {
      float4 w = wwS[k2 * 64 + lane];
#pragma unroll
      for (int n = 0; n < 8; ++n) {
        float4 ao = exS[wv][n][k2];
        out[n] += w.x * ao.x + w.y * ao.y + w.z * ao.z + w.w * ao.w;
      }
    }

    const float sc = scaleS[lane], sh = shiftS[lane], bi = biasS[lane];
#pragma unroll
    for (int n = 0; n < 8; ++n) {
      float o = fmaxf((out[n] + bi) * sc + sh, 0.0f);
      hout[(size_t)(nbase + n) * 64 + lane] = o;
    }
  }
}

// ---------------- reduction over h2: sums[0:64]=Σ h2, sums[64:128]=Σ coef*h2 ----------------

__global__ __launch_bounds__(256) void reduce_kernel(const float* __restrict__ h2,
                                                     const float* __restrict__ coef,
                                                     float* __restrict__ sums) {
  __shared__ float red[4][128];
  int lane = threadIdx.x & 63;
  int wv = threadIdx.x >> 6;
  int gwave = blockIdx.x * 4 + wv;
  int stride = gridDim.x * 4;
  float s0 = 0.f, s1 = 0.f;
  for (int node = gwave; node < N_NODES; node += stride) {
    float val = h2[(size_t)node * 64 + lane];
    float c = coef[node];
    s0 += val;
    s1 += c * val;
  }
  red[wv][lane] = s0;
  red[wv][64 + lane] = s1;
  __syncthreads();
  if (wv == 0) {
    float a = red[0][lane] + red[1][lane] + red[2][lane] + red[3][lane];
    float b = red[0][64 + lane] + red[1][64 + lane] + red[2][64 + lane] + red[3][64 + lane];
    atomicAdd(&sums[lane], a);
    atomicAdd(&sums[64 + lane], b);
  }
}

// ---------------- collapsed layer 2 + classifier + sigmoid ----------------

__global__ void final_kernel(const float* __restrict__ sums,
                             const float* __restrict__ wl2, const float* __restrict__ bl2,
                             const float* __restrict__ wr2,
                             const float* __restrict__ cw1, const float* __restrict__ cb1,
                             const float* __restrict__ cw2, const float* __restrict__ cb2,
                             float* __restrict__ out) {
  __shared__ float maS[64], mhS[64], m3S[64], tS[64];
  int j = threadIdx.x;  // 64 threads
  float invN = 1.0f / (float)N_NODES;
  mhS[j] = sums[j] * invN;        // mean of h2
  maS[j] = sums[64 + j] * invN;   // mean of aggr3
  __syncthreads();
  float acc = bl2[j];
#pragma unroll
  for (int k = 0; k < 64; ++k)
    acc += wl2[j * 64 + k] * maS[k] + wr2[j * 64 + k] * mhS[k];
  m3S[j] = acc;
  __syncthreads();
  float c = cb1[j];
#pragma unroll
  for (int k = 0; k < 64; ++k) c += cw1[j * 64 + k] * m3S[k];
  tS[j] = fmaxf(c, 0.f);
  __syncthreads();
  float r = tS[j] * cw2[j];
#pragma unroll
  for (int off = 32; off > 0; off >>= 1) r += __shfl_down(r, off);
  if (j == 0) out[0] = 1.0f / (1.0f + expf(-(r + cb2[0])));
}

// ---------------- host launcher ----------------

extern "C" void kernel_launch(void* const* d_in, const int* in_sizes, int n_in,
                              void* d_out, int out_size, void* d_ws, size_t ws_size,
                              hipStream_t stream) {
  const float* x   = (const float*)d_in[0];
  const int* ei    = (const int*)d_in[1];
  const float* wl0 = (const float*)d_in[2];
  const float* bl0 = (const float*)d_in[3];
  const float* wr0 = (const float*)d_in[4];
  const float* wl1 = (const float*)d_in[5];
  const float* bl1 = (const float*)d_in[6];
  const float* wr1 = (const float*)d_in[7];
  const float* wl2 = (const float*)d_in[8];
  const float* bl2 = (const float*)d_in[9];
  const float* wr2 = (const float*)d_in[10];
  const float* g0  = (const float*)d_in[11];
  const float* be0 = (const float*)d_in[12];
  const float* m0  = (const float*)d_in[13];
  const float* v0  = (const float*)d_in[14];
  const float* g1  = (const float*)d_in[15];
  const float* be1 = (const float*)d_in[16];
  const float* m1  = (const float*)d_in[17];
  const float* v1  = (const float*)d_in[18];
  const float* cw1 = (const float*)d_in[19];
  const float* cb1 = (const float*)d_in[20];
  const float* cw2 = (const float*)d_in[21];
  const float* cb2 = (const float*)d_in[22];

  const int* srcp = ei;            // edge_index[0]
  const int* dstp = ei + N_EDGES;  // edge_index[1]

  char* ws = (char*)d_ws;
  size_t off = 0;
  auto alloc = [&](size_t bytes) {
    void* p = ws + off;
    off = align256(off + bytes);
    return p;
  };
  int* cnt      = (int*)alloc((size_t)N_NODES * 4);
  int* rowptr   = (int*)alloc((size_t)N_NODES * 4);
  int* fill     = (int*)alloc((size_t)N_NODES * 4);
  int* blocksum = (int*)alloc(128 * 4);
  float* coef   = (float*)alloc((size_t)N_NODES * 4);
  int* col      = (int*)alloc((size_t)N_EDGES * 4);
  float* sums   = (float*)alloc(128 * 4);
  float* h1     = (float*)alloc((size_t)N_NODES * 64 * 4);
  float* h2     = (float*)alloc((size_t)N_NODES * 64 * 4);
  (void)off; (void)ws_size; (void)in_sizes; (void)n_in; (void)out_size;

  hipMemsetAsync(cnt, 0, (size_t)N_NODES * 4, stream);
  hipMemsetAsync(coef, 0, (size_t)N_NODES * 4, stream);
  hipMemsetAsync(sums, 0, 128 * 4, stream);

  int eg4 = (N_EDGES / 4 + 255) / 256;
  hist_kernel<<<eg4, 256, 0, stream>>>(dstp, cnt);
  scan1_kernel<<<NCHUNK, SCAN_T, 0, stream>>>(cnt, rowptr, blocksum);
  scan2_kernel<<<1, 128, 0, stream>>>(blocksum, NCHUNK);
  scan3_kernel<<<NCHUNK, SCAN_T, 0, stream>>>(rowptr, fill, blocksum);
  scatter_coef_kernel<<<eg4, 256, 0, stream>>>(srcp, dstp, cnt, fill, col, coef);

  layer_kernel<<<512, 512, 0, stream>>>(x, rowptr, cnt, col, wl0, bl0, wr0,
                                        g0, be0, m0, v0, h1);
  layer_kernel<<<512, 512, 0, stream>>>(h1, rowptr, cnt, col, wl1, bl1, wr1,
                                        g1, be1, m1, v1, h2);
  reduce_kernel<<<512, 256, 0, stream>>>(h2, coef, sums);
  final_kernel<<<1, 64, 0, stream>>>(sums, wl2, bl2, wr2, cw1, cb1, cw2, cb2,
                                     (float*)d_out);
}